// Round 7
// baseline (976.292 us; speedup 1.0000x reference)
//
#include <hip/hip_runtime.h>
#include <hip/hip_bf16.h>

typedef float f32x4 __attribute__((ext_vector_type(4)));
typedef float f32x2 __attribute__((ext_vector_type(2)));
typedef unsigned short u16x2 __attribute__((ext_vector_type(2)));
typedef unsigned short u16x4 __attribute__((ext_vector_type(4)));
typedef unsigned short u16x8 __attribute__((ext_vector_type(8)));
typedef short s16x8 __attribute__((ext_vector_type(8)));   // MFMA A/B fragment (8 bf16)

#define NN 200000
#define NE 400000
#define NG 4096
#define SCHUNK 1024
#define NSCAN ((NN + SCHUNK - 1) / SCHUNK)   // 196

template<int C> struct VecT;
template<> struct VecT<2> { using T = u16x2; };
template<> struct VecT<4> { using T = u16x4; };

__device__ __forceinline__ unsigned short f2bf(float f) {
    union { float f; unsigned int u; } v; v.f = f;
    unsigned int r = v.u + 0x7FFF + ((v.u >> 16) & 1);   // RNE
    return (unsigned short)(r >> 16);
}
__device__ __forceinline__ float bf2f(unsigned short b) {
    union { unsigned int u; float f; } v; v.u = ((unsigned int)b) << 16;
    return v.f;
}

// ---- int64-vs-int32 index detection ----
__global__ void detect_i64(const int* __restrict__ ei, int* __restrict__ flag) {
    unsigned long long m = __ballot(ei[threadIdx.x * 2 + 1] == 0);
    if (threadIdx.x == 0) *flag = (~m == 0ULL) ? 1 : 0;
}
__device__ __forceinline__ int load_idx(const int* p, long long i, int f64) {
    return f64 ? (int)((const long long*)p)[i] : p[i];
}

// ---- batch -> int32 (once; removes f64 branching from hot epilogue) ----
__global__ __launch_bounds__(256) void bat_conv(const int* __restrict__ bat,
                                                const int* __restrict__ flag,
                                                int* __restrict__ bat32) {
    int i = blockIdx.x * 256 + threadIdx.x;
    if (i < NN) bat32[i] = *flag ? (int)((const long long*)bat)[i] : bat[i];
}

// ---------------- weight convert+transpose: Wt[n][k] = bf16(W[k][n]) ----------------
__global__ void wt_conv(const float* __restrict__ W, unsigned short* __restrict__ Wt,
                        int K, int N) {
    int tid = blockIdx.x * 256 + threadIdx.x;
    if (tid >= K * N) return;
    int n = tid / K, k = tid - n * K;
    Wt[tid] = f2bf(W[(size_t)k * N + n]);
}

// ---------------- x (f32) -> xh (bf16), sequential ----------------
__global__ __launch_bounds__(256) void x2bf(const float* __restrict__ x,
                                            unsigned short* __restrict__ xh) {
    long long i = ((long long)blockIdx.x * 256 + threadIdx.x) * 4;
    if (i >= (long long)NN * 128) return;
    f32x4 v = *(const f32x4*)(x + i);
    u16x4 o; o.x = f2bf(v.x); o.y = f2bf(v.y); o.z = f2bf(v.z); o.w = f2bf(v.w);
    *(u16x4*)(xh + i) = o;
}

// ---------------- permute edge_attr into CSR order (once, reused 2x) ----------------
__global__ __launch_bounds__(256) void ea_perm(const float* __restrict__ ea,
                                               const int* __restrict__ eidx,
                                               const int* __restrict__ totE_p,
                                               float* __restrict__ eac) {
    int j = blockIdx.x * 256 + threadIdx.x;
    if (j >= *totE_p) return;
    int e = eidx[j];
    if ((unsigned)e >= NE) e = 0;
    const float* s = ea + (size_t)e * 16;
    float* d = eac + (size_t)j * 16;
#pragma unroll
    for (int k = 0; k < 4; ++k)
        *(f32x4*)(d + k * 4) = *(const f32x4*)(s + k * 4);
}

// ---------------- CSR build: histogram -> scan -> fill ----------------
__global__ __launch_bounds__(256) void hist_dst(const int* __restrict__ ei,
                                                const int* __restrict__ flag,
                                                int* __restrict__ deg) {
    int e = blockIdx.x * 256 + threadIdx.x;
    if (e >= NE) return;
    int f64 = *flag;
    int s = load_idx(ei, e, f64);
    int d = load_idx(ei, (long long)NE + e, f64);
    if ((unsigned)s < NN && (unsigned)d < NN) atomicAdd(&deg[d], 1);
}

__global__ __launch_bounds__(256) void scan_bsum(const int* __restrict__ deg,
                                                 int* __restrict__ bsum) {
    __shared__ int red[256];
    int t = threadIdx.x, base = blockIdx.x * SCHUNK + t * 4;
    int s = 0;
#pragma unroll
    for (int c = 0; c < 4; ++c) { int i = base + c; if (i < NN) s += deg[i]; }
    red[t] = s; __syncthreads();
    for (int o = 128; o > 0; o >>= 1) { if (t < o) red[t] += red[t + o]; __syncthreads(); }
    if (t == 0) bsum[blockIdx.x] = red[0];
}

__global__ void scan_carry(int* __restrict__ bsum, int* __restrict__ rowptr_end) {
    if (threadIdx.x == 0) {
        int run = 0;
        for (int i = 0; i < NSCAN; ++i) { int v = bsum[i]; bsum[i] = run; run += v; }
        *rowptr_end = run;   // rowptr[NN] = totE
    }
}

// scan_final also seeds cursor (folds the old copy_int launch)
__global__ __launch_bounds__(256) void scan_final(const int* __restrict__ deg,
                                                  const int* __restrict__ bsum,
                                                  int* __restrict__ rowptr,
                                                  int* __restrict__ cursor) {
    __shared__ int lds[256];
    int t = threadIdx.x, base = blockIdx.x * SCHUNK + t * 4;
    int v[4], s = 0;
#pragma unroll
    for (int c = 0; c < 4; ++c) { int i = base + c; v[c] = (i < NN) ? deg[i] : 0; s += v[c]; }
    lds[t] = s; __syncthreads();
    for (int o = 1; o < 256; o <<= 1) {
        int x = 0;
        if (t >= o) x = lds[t - o];
        __syncthreads();
        if (t >= o) lds[t] += x;
        __syncthreads();
    }
    int run = lds[t] - s + bsum[blockIdx.x];
#pragma unroll
    for (int c = 0; c < 4; ++c) {
        int i = base + c;
        if (i < NN) { rowptr[i] = run; cursor[i] = run; }
        run += v[c];
    }
}

__global__ __launch_bounds__(256) void fill_csr(const int* __restrict__ ei,
                                                const int* __restrict__ flag,
                                                int* __restrict__ cursor,
                                                int* __restrict__ srcs,
                                                int* __restrict__ eidx) {
    int e = blockIdx.x * 256 + threadIdx.x;
    if (e >= NE) return;
    int f64 = *flag;
    int s = load_idx(ei, e, f64);
    int d = load_idx(ei, (long long)NE + e, f64);
    if ((unsigned)s >= NN || (unsigned)d >= NN) return;
    int pos = atomicAdd(&cursor[d], 1);
    if ((unsigned)pos < NE) { srcs[pos] = s; eidx[pos] = e; }
}

// ---------------- stage 1: edge-parallel message build (U edges/wave, one shot) ----------------
template<int C, int U>
__global__ __launch_bounds__(256)
void msg_build(const unsigned short* __restrict__ xh,
               const float* __restrict__ eac,
               const float* __restrict__ We, const float* __restrict__ be,
               const int* __restrict__ srcs, const int* __restrict__ totE_p,
               unsigned short* __restrict__ M) {
    using XV = typename VecT<C>::T;
    constexpr int D = 64 * C;
    constexpr int C2 = C / 2;
    const int wid  = (blockIdx.x * 256 + threadIdx.x) >> 6;
    const int lane = threadIdx.x & 63;
    const int totE = *totE_p;
    const int col = lane * C;

    f32x2 w2[16][C2], bb2[C2];
#pragma unroll
    for (int k = 0; k < 16; ++k)
#pragma unroll
        for (int c = 0; c < C2; ++c)
            w2[k][c] = *(const f32x2*)(We + k * D + col + 2 * c);
#pragma unroll
    for (int c = 0; c < C2; ++c) bb2[c] = *(const f32x2*)(be + col + 2 * c);

    const int j0 = wid * U;
    int sv[U];
    XV xv[U];
#pragma unroll
    for (int u = 0; u < U; ++u) {
        int j = j0 + u;
        sv[u] = (j < totE) ? srcs[j] : -1;
    }
#pragma unroll
    for (int u = 0; u < U; ++u) {
        if ((unsigned)sv[u] < NN)
            xv[u] = *(const XV*)(xh + (size_t)sv[u] * D + col);
        else
            xv[u] = (XV)0;
    }
#pragma unroll
    for (int u = 0; u < U; ++u) {
        int j = j0 + u;
        if (j >= totE) continue;
        const float* eap = eac + (size_t)j * 16;
        f32x4 e0 = *(const f32x4*)eap;
        f32x4 e1 = *(const f32x4*)(eap + 4);
        f32x4 e2 = *(const f32x4*)(eap + 8);
        f32x4 e3 = *(const f32x4*)(eap + 12);
        f32x2 m2[C2];
#pragma unroll
        for (int c = 0; c < C2; ++c) {
            f32x2 xx; xx.x = bf2f(xv[u][2 * c]); xx.y = bf2f(xv[u][2 * c + 1]);
            m2[c] = bb2[c] + xx;
        }
#pragma unroll
        for (int k = 0; k < 4; ++k) {
            f32x2 k0; k0.x = e0[k]; k0.y = e0[k];
            f32x2 k1; k1.x = e1[k]; k1.y = e1[k];
            f32x2 k2; k2.x = e2[k]; k2.y = e2[k];
            f32x2 k3; k3.x = e3[k]; k3.y = e3[k];
#pragma unroll
            for (int c = 0; c < C2; ++c) {
                m2[c] += k0 * w2[k][c];
                m2[c] += k1 * w2[4 + k][c];
                m2[c] += k2 * w2[8 + k][c];
                m2[c] += k3 * w2[12 + k][c];
            }
        }
        XV o;
#pragma unroll
        for (int c = 0; c < C2; ++c) {
            o[2 * c]     = f2bf(fmaxf(m2[c].x, 0.f));
            o[2 * c + 1] = f2bf(fmaxf(m2[c].y, 0.f));
        }
        *(XV*)(M + (size_t)j * D + col) = o;
    }
}

// ---------------- stage 2: segment-sum ----------------
template<int C>
__global__ __launch_bounds__(256)
void seg_sum(const unsigned short* __restrict__ M, const int* __restrict__ rowptr,
             const unsigned short* __restrict__ self, unsigned short* __restrict__ outp) {
    using XV = typename VecT<C>::T;
    constexpr int D = 64 * C;
    const int node = (blockIdx.x * 256 + threadIdx.x) >> 6;
    const int lane = threadIdx.x & 63;
    if (node >= NN) return;
    const int col = lane * C;
    int lo = rowptr[node], hi = rowptr[node + 1];
    if (lo > hi || (unsigned)hi > NE) { lo = 0; hi = 0; }

    float a[C];
    XV sv = *(const XV*)(self + (size_t)node * D + col);
#pragma unroll
    for (int c = 0; c < C; ++c) a[c] = bf2f(sv[c]);

    int j = lo;
    for (; j + 1 < hi; j += 2) {
        XV m0 = *(const XV*)(M + (size_t)j * D + col);
        XV m1 = *(const XV*)(M + (size_t)(j + 1) * D + col);
#pragma unroll
        for (int c = 0; c < C; ++c) a[c] += bf2f(m0[c]) + bf2f(m1[c]);
    }
    if (j < hi) {
        XV m0 = *(const XV*)(M + (size_t)j * D + col);
#pragma unroll
        for (int c = 0; c < C; ++c) a[c] += bf2f(m0[c]);
    }
    XV o;
#pragma unroll
    for (int c = 0; c < C; ++c) o[c] = f2bf(a[c]);
    *(XV*)(outp + (size_t)node * D + col) = o;
}

// ------- fused double GEMM v5: C = relu(relu(A@Wa+ba)@Wb+bb), optional fused mean-pool -------
// r6 post-mortem: schedule changes (r3/r5/r6) all pinned at 170-190us with every
// pipe ~12% busy -> the constraint is TLP (2.4 blocks/CU), not the schedule.
// v5 keeps r6's proven barrier-free structure, halves the tile:
//  * 32-row blocks (grid 6250), acc[2][4] = 32 VGPR, LDS 16.6 KB.
//  * VGPR ~<=128 + launch_bounds(256,4) -> 4 blocks = 16 waves/CU (was 9.6):
//    ~1.7x the independent latency chains per SIMD, finer grid tail.
//  * Same 3 barriers/block; B direct-from-L2 register rotation (r6-proven).
// Bank scheme: LDA (132/260 shorts = 66/130 dw) === 2 mod 32 (proven, max 2-way).
template<int K1, int MODE>   // MODE 0: write bf16 C; MODE 1: fused mean-pool, no C write
__global__ __launch_bounds__(256, 4)
void gemm2_fused(const unsigned short* __restrict__ A,
                 const unsigned short* __restrict__ Wta, const float* __restrict__ ba,
                 const unsigned short* __restrict__ Wtb, const float* __restrict__ bb,
                 unsigned short* __restrict__ C,
                 float* __restrict__ sums, const int* __restrict__ bat32) {
    constexpr int LDA = K1 + 4;
    constexpr int LDM = 260;                    // 256 + 4 shorts
    __shared__ unsigned short Us[32 * LDM];     // 16.6 KB: A (phase1) then Ms (phase2)
    const int m0 = blockIdx.x * 32;
    const int tid = threadIdx.x;
    const int wave = tid >> 6;
    const int lane = tid & 63;
    const int lm = lane & 15;
    const int lq = lane >> 4;
    const int nw = wave * 64;                   // wave n-offset

    // ---- stage A once: 32 rows x K1 (8 threads/row, 8-short interleaved segments) ----
    {
        const int arow = tid >> 3;
        const int acol = (tid & 7) * 8;
        const unsigned short* src = A + (size_t)(m0 + arow) * K1;
        unsigned short* dst = Us + arow * LDA;
#pragma unroll
        for (int c = 0; c < K1 / 64; ++c)
            *(u16x8*)(dst + acol + c * 64) = *(const u16x8*)(src + acol + c * 64);
    }

    // B-fragment direct loads: 16 rows x 64 B per fragment, L2-hot weights.
    auto ldb = [&](const unsigned short* W, int KW, int k0, s16x8* bf) {
#pragma unroll
        for (int nt = 0; nt < 4; ++nt)
            bf[nt] = *(const s16x8*)(W + (size_t)(nw + nt * 16 + lm) * KW + k0 + lq * 8);
    };

    f32x4 acc[2][4] = {};
    s16x8 bcur[4], bnxt[4];

    ldb(Wta, K1, 0, bcur);
    __syncthreads();                            // A staged

    // ================= phase 1: mid = relu(A @ Wa + ba), barrier-free =================
    for (int k0 = 0; k0 < K1; k0 += 32) {
        if (k0 + 32 < K1) ldb(Wta, K1, k0 + 32, bnxt);
        else              ldb(Wtb, 256, 0, bnxt);    // prefetch phase-2 chunk 0
        s16x8 af[2];
#pragma unroll
        for (int mt = 0; mt < 2; ++mt)
            af[mt] = *(const s16x8*)(Us + (mt * 16 + lm) * LDA + k0 + lq * 8);
#pragma unroll
        for (int mt = 0; mt < 2; ++mt)
#pragma unroll
            for (int nt = 0; nt < 4; ++nt)
                acc[mt][nt] = __builtin_amdgcn_mfma_f32_16x16x32_bf16(
                    af[mt], bcur[nt], acc[mt][nt], 0, 0, 0);
#pragma unroll
        for (int nt = 0; nt < 4; ++nt) bcur[nt] = bnxt[nt];
    }

    __syncthreads();                            // all phase-1 reads of Us done

    // ---- mid epilogue -> Us as Ms ----
#pragma unroll
    for (int mt = 0; mt < 2; ++mt) {
        const int row = mt * 16 + lq * 4;
#pragma unroll
        for (int nt = 0; nt < 4; ++nt) {
            int coln = nw + nt * 16 + lm;
            float bv = ba[coln];
#pragma unroll
            for (int r = 0; r < 4; ++r) {
                float v = fmaxf(acc[mt][nt][r] + bv, 0.f);
                Us[(row + r) * LDM + coln] = f2bf(v);
                acc[mt][nt][r] = 0.f;           // re-zero for phase 2
            }
        }
    }
    __syncthreads();                            // Ms visible

    // ================= phase 2: out = relu(mid @ Wb + bb), barrier-free =================
    for (int k0 = 0; k0 < 256; k0 += 32) {
        if (k0 + 32 < 256) ldb(Wtb, 256, k0 + 32, bnxt);
        s16x8 af[2];
#pragma unroll
        for (int mt = 0; mt < 2; ++mt)
            af[mt] = *(const s16x8*)(Us + (mt * 16 + lm) * LDM + k0 + lq * 8);
#pragma unroll
        for (int mt = 0; mt < 2; ++mt)
#pragma unroll
            for (int nt = 0; nt < 4; ++nt)
                acc[mt][nt] = __builtin_amdgcn_mfma_f32_16x16x32_bf16(
                    af[mt], bcur[nt], acc[mt][nt], 0, 0, 0);
#pragma unroll
        for (int nt = 0; nt < 4; ++nt) bcur[nt] = bnxt[nt];
    }

    // ---- epilogue: C/D layout col=lane&15, row=(lane>>4)*4+reg ----
    if constexpr (MODE == 0) {
#pragma unroll
        for (int mt = 0; mt < 2; ++mt) {
            const int row = m0 + mt * 16 + lq * 4;
#pragma unroll
            for (int nt = 0; nt < 4; ++nt) {
                int coln = nw + nt * 16 + lm;
                float bv = bb[coln];
#pragma unroll
                for (int r = 0; r < 4; ++r) {
                    float v = fmaxf(acc[mt][nt][r] + bv, 0.f);
                    C[(size_t)(row + r) * 256 + coln] = f2bf(v);
                }
            }
        }
    } else {
        // fused mean-pool: lane's 8 rows are monotone in graph id (batch sorted)
        int g8[8];
#pragma unroll
        for (int mt = 0; mt < 2; ++mt)
#pragma unroll
            for (int r = 0; r < 4; ++r)
                g8[mt * 4 + r] = bat32[m0 + mt * 16 + lq * 4 + r];
#pragma unroll
        for (int nt = 0; nt < 4; ++nt) {
            int coln = nw + nt * 16 + lm;
            float bv = bb[coln];
            int curg = g8[0];
            float s = 0.f;
#pragma unroll
            for (int i = 0; i < 8; ++i) {
                float v = fmaxf(acc[i >> 2][nt][i & 3] + bv, 0.f);
                if (g8[i] != curg) {
                    if ((unsigned)curg < NG) atomicAdd(&sums[(size_t)curg * 256 + coln], s);
                    curg = g8[i]; s = 0.f;
                }
                s += v;
            }
            if ((unsigned)curg < NG) atomicAdd(&sums[(size_t)curg * 256 + coln], s);
        }
    }
}

// ------- pool divide: out[g] = sums[g] / max(count_g, 1) -------
__global__ __launch_bounds__(256)
void pool_div(const float* __restrict__ sums, const int* __restrict__ bat32,
              float* __restrict__ out) {
    int g = blockIdx.x;
    int a = 0, b = NN;
    while (a < b) { int m = (a + b) >> 1; if (bat32[m] < g) a = m + 1; else b = m; }
    int lo = a;
    b = NN;
    while (a < b) { int m = (a + b) >> 1; if (bat32[m] < g + 1) a = m + 1; else b = m; }
    float inv = 1.f / fmaxf((float)(a - lo), 1.f);
    out[(size_t)g * 256 + threadIdx.x] = sums[(size_t)g * 256 + threadIdx.x] * inv;
}

extern "C" void kernel_launch(void* const* d_in, const int* in_sizes, int n_in,
                              void* d_out, int out_size, void* d_ws, size_t ws_size,
                              hipStream_t stream) {
    const float* x   = (const float*)d_in[0];
    const float* ea  = (const float*)d_in[1];
    const float* We1 = (const float*)d_in[2];
    const float* be1 = (const float*)d_in[3];
    const float* W1a = (const float*)d_in[4];
    const float* b1a = (const float*)d_in[5];
    const float* W1b = (const float*)d_in[6];
    const float* b1b = (const float*)d_in[7];
    const float* We2 = (const float*)d_in[8];
    const float* be2 = (const float*)d_in[9];
    const float* W2a = (const float*)d_in[10];
    const float* b2a = (const float*)d_in[11];
    const float* W2b = (const float*)d_in[12];
    const float* b2b = (const float*)d_in[13];
    const int*   ei  = (const int*)d_in[14];
    const int*   bat = (const int*)d_in[15];
    float* out = (float*)d_out;

    // ---- workspace (within proven 410 MB footprint) ----
    char* ws = (char*)d_ws;
    const size_t SZH = (size_t)NN * 256 * 2;   // 102,400,000
    unsigned short* A  = (unsigned short*)ws;
    unsigned short* B  = (unsigned short*)(ws + SZH);   // M2 spans B..(B+2*SZH)
    char* Dr = ws + 3 * SZH;
    char* q = Dr;
    int* deg    = (int*)q; q += (size_t)NN * 4;
    int* rowptr = (int*)q; q += (size_t)(NN + 1) * 4;
    int* cursor = (int*)q; q += (size_t)NN * 4;
    int* srcs   = (int*)q; q += (size_t)NE * 4;
    int* eidx   = (int*)q; q += (size_t)NE * 4;
    int* bsum   = (int*)q; q += (size_t)NSCAN * 4;
    q = Dr + ((q - Dr + 63) & ~63ll);
    float*          eac = (float*)q; q += (size_t)NE * 16 * 4;          // 25.6 MB
    unsigned short* xh  = (unsigned short*)q; q += (size_t)NN * 128 * 2; // 51.2 MB
    int*   bat32 = (int*)q;   q += (size_t)NN * 4;                      // 0.8 MB
    float* sums  = (float*)q; q += (size_t)NG * 256 * 4;                // 4.2 MB
    char* p = ws + 4 * SZH;
    unsigned short* Wt1a = (unsigned short*)p; p += 128 * 256 * 2;
    unsigned short* Wt1b = (unsigned short*)p; p += 256 * 256 * 2;
    unsigned short* Wt2a = (unsigned short*)p; p += 256 * 256 * 2;
    unsigned short* Wt2b = (unsigned short*)p; p += 256 * 256 * 2;
    int* flag = (int*)p;

    detect_i64<<<1, 64, 0, stream>>>(ei, flag);
    bat_conv<<<(NN + 255) / 256, 256, 0, stream>>>(bat, flag, bat32);
    wt_conv<<<(128 * 256 + 255) / 256, 256, 0, stream>>>(W1a, Wt1a, 128, 256);
    wt_conv<<<(256 * 256 + 255) / 256, 256, 0, stream>>>(W1b, Wt1b, 256, 256);
    wt_conv<<<(256 * 256 + 255) / 256, 256, 0, stream>>>(W2a, Wt2a, 256, 256);
    wt_conv<<<(256 * 256 + 255) / 256, 256, 0, stream>>>(W2b, Wt2b, 256, 256);

    // ---- CSR build (once; shared by both layers) ----
    hipMemsetAsync(deg, 0, (size_t)NN * 4, stream);
    hipMemsetAsync(sums, 0, (size_t)NG * 256 * 4, stream);
    hist_dst<<<(NE + 255) / 256, 256, 0, stream>>>(ei, flag, deg);
    scan_bsum<<<NSCAN, 256, 0, stream>>>(deg, bsum);
    scan_carry<<<1, 64, 0, stream>>>(bsum, rowptr + NN);
    scan_final<<<NSCAN, 256, 0, stream>>>(deg, bsum, rowptr, cursor);
    fill_csr<<<(NE + 255) / 256, 256, 0, stream>>>(ei, flag, cursor, srcs, eidx);
    ea_perm<<<(NE + 255) / 256, 256, 0, stream>>>(ea, eidx, rowptr + NN, eac);
    x2bf<<<(NN * 128 / 4 + 255) / 256, 256, 0, stream>>>(x, xh);

    const int GM_BLK = NE / 32;   // 12500: 4 waves x 8 edge-slots per block
    const int GS_BLK = NN / 4;    // 50000: wave per node
    const int GG_BLK = NN / 32;   // 6250: GEMM m-blocks (32 rows, full N per block)

    // ---- layer 1 (D=128) ----
    msg_build<2, 8><<<GM_BLK, 256, 0, stream>>>(xh, eac, We1, be1, srcs, rowptr + NN, A);  // M1 -> A
    seg_sum<2><<<GS_BLK, 256, 0, stream>>>(A, rowptr, xh, B);                              // hin1 -> B
    gemm2_fused<128, 0><<<GG_BLK, 256, 0, stream>>>(B, Wt1a, b1a, Wt1b, b1b, A,
                                                    nullptr, nullptr);                     // h1 -> A

    // ---- layer 2 (D=256) ----
    msg_build<4, 8><<<GM_BLK, 256, 0, stream>>>(A, eac, We2, be2, srcs, rowptr + NN, B);   // M2 -> B
    seg_sum<4><<<GS_BLK, 256, 0, stream>>>(B, rowptr, A, A);                               // hin2 in-place A
    gemm2_fused<256, 1><<<GG_BLK, 256, 0, stream>>>(A, Wt2a, b2a, Wt2b, b2b, nullptr,
                                                    sums, bat32);                          // pool -> sums

    // ---- mean pool finish ----
    pool_div<<<NG, 256, 0, stream>>>(sums, bat32, out);
}

// Round 8
// 844.782 us; speedup vs baseline: 1.1557x; 1.1557x over previous
//
#include <hip/hip_runtime.h>
#include <hip/hip_bf16.h>

typedef float f32x4 __attribute__((ext_vector_type(4)));
typedef float f32x2 __attribute__((ext_vector_type(2)));
typedef unsigned short u16x2 __attribute__((ext_vector_type(2)));
typedef unsigned short u16x4 __attribute__((ext_vector_type(4)));
typedef unsigned short u16x8 __attribute__((ext_vector_type(8)));
typedef short s16x8 __attribute__((ext_vector_type(8)));   // MFMA A/B fragment (8 bf16)

#define NN 200000
#define NE 400000
#define NG 4096
#define SCHUNK 1024
#define NSCAN ((NN + SCHUNK - 1) / SCHUNK)   // 196

template<int C> struct VecT;
template<> struct VecT<2> { using T = u16x2; };
template<> struct VecT<4> { using T = u16x4; };

__device__ __forceinline__ unsigned short f2bf(float f) {
    union { float f; unsigned int u; } v; v.f = f;
    unsigned int r = v.u + 0x7FFF + ((v.u >> 16) & 1);   // RNE
    return (unsigned short)(r >> 16);
}
__device__ __forceinline__ float bf2f(unsigned short b) {
    union { unsigned int u; float f; } v; v.u = ((unsigned int)b) << 16;
    return v.f;
}

// ---- int64-vs-int32 index detection ----
__global__ void detect_i64(const int* __restrict__ ei, int* __restrict__ flag) {
    unsigned long long m = __ballot(ei[threadIdx.x * 2 + 1] == 0);
    if (threadIdx.x == 0) *flag = (~m == 0ULL) ? 1 : 0;
}
__device__ __forceinline__ int load_idx(const int* p, long long i, int f64) {
    return f64 ? (int)((const long long*)p)[i] : p[i];
}

// ---- batch -> int32 (once; removes f64 branching from hot epilogue) ----
__global__ __launch_bounds__(256) void bat_conv(const int* __restrict__ bat,
                                                const int* __restrict__ flag,
                                                int* __restrict__ bat32) {
    int i = blockIdx.x * 256 + threadIdx.x;
    if (i < NN) bat32[i] = *flag ? (int)((const long long*)bat)[i] : bat[i];
}

// ---------------- weight convert+transpose: Wt[n][k] = bf16(W[k][n]) ----------------
__global__ void wt_conv(const float* __restrict__ W, unsigned short* __restrict__ Wt,
                        int K, int N) {
    int tid = blockIdx.x * 256 + threadIdx.x;
    if (tid >= K * N) return;
    int n = tid / K, k = tid - n * K;
    Wt[tid] = f2bf(W[(size_t)k * N + n]);
}

// ---------------- x (f32) -> xh (bf16), sequential ----------------
__global__ __launch_bounds__(256) void x2bf(const float* __restrict__ x,
                                            unsigned short* __restrict__ xh) {
    long long i = ((long long)blockIdx.x * 256 + threadIdx.x) * 4;
    if (i >= (long long)NN * 128) return;
    f32x4 v = *(const f32x4*)(x + i);
    u16x4 o; o.x = f2bf(v.x); o.y = f2bf(v.y); o.z = f2bf(v.z); o.w = f2bf(v.w);
    *(u16x4*)(xh + i) = o;
}

// ---------------- permute edge_attr into CSR order (once, reused 2x) ----------------
__global__ __launch_bounds__(256) void ea_perm(const float* __restrict__ ea,
                                               const int* __restrict__ eidx,
                                               const int* __restrict__ totE_p,
                                               float* __restrict__ eac) {
    int j = blockIdx.x * 256 + threadIdx.x;
    if (j >= *totE_p) return;
    int e = eidx[j];
    if ((unsigned)e >= NE) e = 0;
    const float* s = ea + (size_t)e * 16;
    float* d = eac + (size_t)j * 16;
#pragma unroll
    for (int k = 0; k < 4; ++k)
        *(f32x4*)(d + k * 4) = *(const f32x4*)(s + k * 4);
}

// ---------------- CSR build: histogram -> scan -> fill ----------------
__global__ __launch_bounds__(256) void hist_dst(const int* __restrict__ ei,
                                                const int* __restrict__ flag,
                                                int* __restrict__ deg) {
    int e = blockIdx.x * 256 + threadIdx.x;
    if (e >= NE) return;
    int f64 = *flag;
    int s = load_idx(ei, e, f64);
    int d = load_idx(ei, (long long)NE + e, f64);
    if ((unsigned)s < NN && (unsigned)d < NN) atomicAdd(&deg[d], 1);
}

__global__ __launch_bounds__(256) void scan_bsum(const int* __restrict__ deg,
                                                 int* __restrict__ bsum) {
    __shared__ int red[256];
    int t = threadIdx.x, base = blockIdx.x * SCHUNK + t * 4;
    int s = 0;
#pragma unroll
    for (int c = 0; c < 4; ++c) { int i = base + c; if (i < NN) s += deg[i]; }
    red[t] = s; __syncthreads();
    for (int o = 128; o > 0; o >>= 1) { if (t < o) red[t] += red[t + o]; __syncthreads(); }
    if (t == 0) bsum[blockIdx.x] = red[0];
}

__global__ void scan_carry(int* __restrict__ bsum, int* __restrict__ rowptr_end) {
    if (threadIdx.x == 0) {
        int run = 0;
        for (int i = 0; i < NSCAN; ++i) { int v = bsum[i]; bsum[i] = run; run += v; }
        *rowptr_end = run;   // rowptr[NN] = totE
    }
}

// scan_final also seeds cursor (folds the old copy_int launch)
__global__ __launch_bounds__(256) void scan_final(const int* __restrict__ deg,
                                                  const int* __restrict__ bsum,
                                                  int* __restrict__ rowptr,
                                                  int* __restrict__ cursor) {
    __shared__ int lds[256];
    int t = threadIdx.x, base = blockIdx.x * SCHUNK + t * 4;
    int v[4], s = 0;
#pragma unroll
    for (int c = 0; c < 4; ++c) { int i = base + c; v[c] = (i < NN) ? deg[i] : 0; s += v[c]; }
    lds[t] = s; __syncthreads();
    for (int o = 1; o < 256; o <<= 1) {
        int x = 0;
        if (t >= o) x = lds[t - o];
        __syncthreads();
        if (t >= o) lds[t] += x;
        __syncthreads();
    }
    int run = lds[t] - s + bsum[blockIdx.x];
#pragma unroll
    for (int c = 0; c < 4; ++c) {
        int i = base + c;
        if (i < NN) { rowptr[i] = run; cursor[i] = run; }
        run += v[c];
    }
}

__global__ __launch_bounds__(256) void fill_csr(const int* __restrict__ ei,
                                                const int* __restrict__ flag,
                                                int* __restrict__ cursor,
                                                int* __restrict__ srcs,
                                                int* __restrict__ eidx) {
    int e = blockIdx.x * 256 + threadIdx.x;
    if (e >= NE) return;
    int f64 = *flag;
    int s = load_idx(ei, e, f64);
    int d = load_idx(ei, (long long)NE + e, f64);
    if ((unsigned)s >= NN || (unsigned)d >= NN) return;
    int pos = atomicAdd(&cursor[d], 1);
    if ((unsigned)pos < NE) { srcs[pos] = s; eidx[pos] = e; }
}

// ---------------- stage 1: edge-parallel message build (U edges/wave, one shot) ----------------
template<int C, int U>
__global__ __launch_bounds__(256)
void msg_build(const unsigned short* __restrict__ xh,
               const float* __restrict__ eac,
               const float* __restrict__ We, const float* __restrict__ be,
               const int* __restrict__ srcs, const int* __restrict__ totE_p,
               unsigned short* __restrict__ M) {
    using XV = typename VecT<C>::T;
    constexpr int D = 64 * C;
    constexpr int C2 = C / 2;
    const int wid  = (blockIdx.x * 256 + threadIdx.x) >> 6;
    const int lane = threadIdx.x & 63;
    const int totE = *totE_p;
    const int col = lane * C;

    f32x2 w2[16][C2], bb2[C2];
#pragma unroll
    for (int k = 0; k < 16; ++k)
#pragma unroll
        for (int c = 0; c < C2; ++c)
            w2[k][c] = *(const f32x2*)(We + k * D + col + 2 * c);
#pragma unroll
    for (int c = 0; c < C2; ++c) bb2[c] = *(const f32x2*)(be + col + 2 * c);

    const int j0 = wid * U;
    int sv[U];
    XV xv[U];
#pragma unroll
    for (int u = 0; u < U; ++u) {
        int j = j0 + u;
        sv[u] = (j < totE) ? srcs[j] : -1;
    }
#pragma unroll
    for (int u = 0; u < U; ++u) {
        if ((unsigned)sv[u] < NN)
            xv[u] = *(const XV*)(xh + (size_t)sv[u] * D + col);
        else
            xv[u] = (XV)0;
    }
#pragma unroll
    for (int u = 0; u < U; ++u) {
        int j = j0 + u;
        if (j >= totE) continue;
        const float* eap = eac + (size_t)j * 16;
        f32x4 e0 = *(const f32x4*)eap;
        f32x4 e1 = *(const f32x4*)(eap + 4);
        f32x4 e2 = *(const f32x4*)(eap + 8);
        f32x4 e3 = *(const f32x4*)(eap + 12);
        f32x2 m2[C2];
#pragma unroll
        for (int c = 0; c < C2; ++c) {
            f32x2 xx; xx.x = bf2f(xv[u][2 * c]); xx.y = bf2f(xv[u][2 * c + 1]);
            m2[c] = bb2[c] + xx;
        }
#pragma unroll
        for (int k = 0; k < 4; ++k) {
            f32x2 k0; k0.x = e0[k]; k0.y = e0[k];
            f32x2 k1; k1.x = e1[k]; k1.y = e1[k];
            f32x2 k2; k2.x = e2[k]; k2.y = e2[k];
            f32x2 k3; k3.x = e3[k]; k3.y = e3[k];
#pragma unroll
            for (int c = 0; c < C2; ++c) {
                m2[c] += k0 * w2[k][c];
                m2[c] += k1 * w2[4 + k][c];
                m2[c] += k2 * w2[8 + k][c];
                m2[c] += k3 * w2[12 + k][c];
            }
        }
        XV o;
#pragma unroll
        for (int c = 0; c < C2; ++c) {
            o[2 * c]     = f2bf(fmaxf(m2[c].x, 0.f));
            o[2 * c + 1] = f2bf(fmaxf(m2[c].y, 0.f));
        }
        *(XV*)(M + (size_t)j * D + col) = o;
    }
}

// ---------------- stage 2: segment-sum ----------------
template<int C>
__global__ __launch_bounds__(256)
void seg_sum(const unsigned short* __restrict__ M, const int* __restrict__ rowptr,
             const unsigned short* __restrict__ self, unsigned short* __restrict__ outp) {
    using XV = typename VecT<C>::T;
    constexpr int D = 64 * C;
    const int node = (blockIdx.x * 256 + threadIdx.x) >> 6;
    const int lane = threadIdx.x & 63;
    if (node >= NN) return;
    const int col = lane * C;
    int lo = rowptr[node], hi = rowptr[node + 1];
    if (lo > hi || (unsigned)hi > NE) { lo = 0; hi = 0; }

    float a[C];
    XV sv = *(const XV*)(self + (size_t)node * D + col);
#pragma unroll
    for (int c = 0; c < C; ++c) a[c] = bf2f(sv[c]);

    int j = lo;
    for (; j + 1 < hi; j += 2) {
        XV m0 = *(const XV*)(M + (size_t)j * D + col);
        XV m1 = *(const XV*)(M + (size_t)(j + 1) * D + col);
#pragma unroll
        for (int c = 0; c < C; ++c) a[c] += bf2f(m0[c]) + bf2f(m1[c]);
    }
    if (j < hi) {
        XV m0 = *(const XV*)(M + (size_t)j * D + col);
#pragma unroll
        for (int c = 0; c < C; ++c) a[c] += bf2f(m0[c]);
    }
    XV o;
#pragma unroll
    for (int c = 0; c < C; ++c) o[c] = f2bf(a[c]);
    *(XV*)(outp + (size_t)node * D + col) = o;
}

// ------- fused double GEMM v6: C = relu(relu(A@Wa+ba)@Wb+bb), optional fused mean-pool -------
// r7 post-mortem: TLP is NOT the limiter (occupancy 30->43% made it WORSE: per-block
// B traffic is constant, so smaller tiles doubled L2 B-traffic). Revert to r6's
// 64-row tile. r6's residual stall: 1-deep B prefetch gives only ~130cy of MFMA
// between load issue and use vs ~200cy L2 latency -> every k-iter exposes stall.
// v6 = r6 + 2-deep B register rotation (b0/b1/b2, unified Wta->Wtb chunk stream):
// issue-to-use distance ~2x16 MFMA ~260cy > L2 latency. Register-only change;
// occupancy held constant (launch_bounds(256,3)) to isolate the ILP effect.
template<int K1, int MODE>   // MODE 0: write bf16 C; MODE 1: fused mean-pool, no C write
__global__ __launch_bounds__(256, 3)
void gemm2_fused(const unsigned short* __restrict__ A,
                 const unsigned short* __restrict__ Wta, const float* __restrict__ ba,
                 const unsigned short* __restrict__ Wtb, const float* __restrict__ bb,
                 unsigned short* __restrict__ C,
                 float* __restrict__ sums, const int* __restrict__ bat32) {
    constexpr int LDA = K1 + 4;
    constexpr int LDM = 260;                    // 256 + 4 shorts
    constexpr int P1 = K1 / 32;                 // phase-1 chunk count
    constexpr int NC = P1 + 8;                  // total chunks (Wta then Wtb)
    __shared__ unsigned short Us[64 * LDM];     // 33.3 KB: A (phase1) then Ms (phase2)
    const int m0 = blockIdx.x * 64;
    const int tid = threadIdx.x;
    const int wave = tid >> 6;
    const int lane = tid & 63;
    const int lm = lane & 15;
    const int lq = lane >> 4;
    const int nw = wave * 64;                   // wave n-offset

    // ---- stage A once: 64 rows x K1 (4 threads/row, 8-short strided segments) ----
    {
        const int arow = tid >> 2;
        const int acol = (tid & 3) * 8;
        const unsigned short* src = A + (size_t)(m0 + arow) * K1;
        unsigned short* dst = Us + arow * LDA;
#pragma unroll
        for (int c = 0; c < K1 / 32; ++c)
            *(u16x8*)(dst + acol + c * 32) = *(const u16x8*)(src + acol + c * 32);
    }

    // unified B chunk stream: chunk c<P1 -> Wta k0=c*32; else Wtb k0=(c-P1)*32.
    // fragment = 16 rows (lm) x 64 B (lq*8 within the 32-k window), L2-hot weights.
    auto ldbc = [&](int c, s16x8* bf) {
        if (c >= NC) return;
        const unsigned short* W = (c < P1) ? Wta : Wtb;
        const int KW = (c < P1) ? K1 : 256;
        const int k0 = (c < P1) ? c * 32 : (c - P1) * 32;
#pragma unroll
        for (int nt = 0; nt < 4; ++nt)
            bf[nt] = *(const s16x8*)(W + (size_t)(nw + nt * 16 + lm) * KW + k0 + lq * 8);
    };

    f32x4 acc[4][4] = {};
    s16x8 b0[4], b1[4], b2[4];

    ldbc(0, b0);                                // chunk 0 in flight
    ldbc(1, b1);                                // chunk 1 in flight (2-deep)
    __syncthreads();                            // A staged

    // ================= phase 1: mid = relu(A @ Wa + ba), barrier-free =================
#pragma unroll
    for (int i = 0; i < P1; ++i) {
        ldbc(i + 2, b2);                        // 2 iterations ahead
        const int k0 = i * 32;
        s16x8 af[4];
#pragma unroll
        for (int mt = 0; mt < 4; ++mt)
            af[mt] = *(const s16x8*)(Us + (mt * 16 + lm) * LDA + k0 + lq * 8);
#pragma unroll
        for (int mt = 0; mt < 4; ++mt)
#pragma unroll
            for (int nt = 0; nt < 4; ++nt)
                acc[mt][nt] = __builtin_amdgcn_mfma_f32_16x16x32_bf16(
                    af[mt], b0[nt], acc[mt][nt], 0, 0, 0);
#pragma unroll
        for (int nt = 0; nt < 4; ++nt) { b0[nt] = b1[nt]; b1[nt] = b2[nt]; }
    }

    __syncthreads();                            // all phase-1 reads of Us done

    // ---- mid epilogue -> Us as Ms ----
#pragma unroll
    for (int mt = 0; mt < 4; ++mt) {
        const int row = mt * 16 + lq * 4;
#pragma unroll
        for (int nt = 0; nt < 4; ++nt) {
            int coln = nw + nt * 16 + lm;
            float bv = ba[coln];
#pragma unroll
            for (int r = 0; r < 4; ++r) {
                float v = fmaxf(acc[mt][nt][r] + bv, 0.f);
                Us[(row + r) * LDM + coln] = f2bf(v);
                acc[mt][nt][r] = 0.f;           // re-zero for phase 2
            }
        }
    }
    __syncthreads();                            // Ms visible

    // ================= phase 2: out = relu(mid @ Wb + bb), barrier-free =================
#pragma unroll
    for (int j = 0; j < 8; ++j) {
        ldbc(P1 + j + 2, b2);
        const int k0 = j * 32;
        s16x8 af[4];
#pragma unroll
        for (int mt = 0; mt < 4; ++mt)
            af[mt] = *(const s16x8*)(Us + (mt * 16 + lm) * LDM + k0 + lq * 8);
#pragma unroll
        for (int mt = 0; mt < 4; ++mt)
#pragma unroll
            for (int nt = 0; nt < 4; ++nt)
                acc[mt][nt] = __builtin_amdgcn_mfma_f32_16x16x32_bf16(
                    af[mt], b0[nt], acc[mt][nt], 0, 0, 0);
#pragma unroll
        for (int nt = 0; nt < 4; ++nt) { b0[nt] = b1[nt]; b1[nt] = b2[nt]; }
    }

    // ---- epilogue: C/D layout col=lane&15, row=(lane>>4)*4+reg ----
    if constexpr (MODE == 0) {
#pragma unroll
        for (int mt = 0; mt < 4; ++mt) {
            const int row = m0 + mt * 16 + lq * 4;
#pragma unroll
            for (int nt = 0; nt < 4; ++nt) {
                int coln = nw + nt * 16 + lm;
                float bv = bb[coln];
#pragma unroll
                for (int r = 0; r < 4; ++r) {
                    float v = fmaxf(acc[mt][nt][r] + bv, 0.f);
                    C[(size_t)(row + r) * 256 + coln] = f2bf(v);
                }
            }
        }
    } else {
        // fused mean-pool: lane's 16 rows are monotone in graph id (batch sorted)
        int g16[16];
#pragma unroll
        for (int mt = 0; mt < 4; ++mt)
#pragma unroll
            for (int r = 0; r < 4; ++r)
                g16[mt * 4 + r] = bat32[m0 + mt * 16 + lq * 4 + r];
#pragma unroll
        for (int nt = 0; nt < 4; ++nt) {
            int coln = nw + nt * 16 + lm;
            float bv = bb[coln];
            int curg = g16[0];
            float s = 0.f;
#pragma unroll
            for (int i = 0; i < 16; ++i) {
                float v = fmaxf(acc[i >> 2][nt][i & 3] + bv, 0.f);
                if (g16[i] != curg) {
                    if ((unsigned)curg < NG) atomicAdd(&sums[(size_t)curg * 256 + coln], s);
                    curg = g16[i]; s = 0.f;
                }
                s += v;
            }
            if ((unsigned)curg < NG) atomicAdd(&sums[(size_t)curg * 256 + coln], s);
        }
    }
}

// ------- pool divide: out[g] = sums[g] / max(count_g, 1) -------
__global__ __launch_bounds__(256)
void pool_div(const float* __restrict__ sums, const int* __restrict__ bat32,
              float* __restrict__ out) {
    int g = blockIdx.x;
    int a = 0, b = NN;
    while (a < b) { int m = (a + b) >> 1; if (bat32[m] < g) a = m + 1; else b = m; }
    int lo = a;
    b = NN;
    while (a < b) { int m = (a + b) >> 1; if (bat32[m] < g + 1) a = m + 1; else b = m; }
    float inv = 1.f / fmaxf((float)(a - lo), 1.f);
    out[(size_t)g * 256 + threadIdx.x] = sums[(size_t)g * 256 + threadIdx.x] * inv;
}

extern "C" void kernel_launch(void* const* d_in, const int* in_sizes, int n_in,
                              void* d_out, int out_size, void* d_ws, size_t ws_size,
                              hipStream_t stream) {
    const float* x   = (const float*)d_in[0];
    const float* ea  = (const float*)d_in[1];
    const float* We1 = (const float*)d_in[2];
    const float* be1 = (const float*)d_in[3];
    const float* W1a = (const float*)d_in[4];
    const float* b1a = (const float*)d_in[5];
    const float* W1b = (const float*)d_in[6];
    const float* b1b = (const float*)d_in[7];
    const float* We2 = (const float*)d_in[8];
    const float* be2 = (const float*)d_in[9];
    const float* W2a = (const float*)d_in[10];
    const float* b2a = (const float*)d_in[11];
    const float* W2b = (const float*)d_in[12];
    const float* b2b = (const float*)d_in[13];
    const int*   ei  = (const int*)d_in[14];
    const int*   bat = (const int*)d_in[15];
    float* out = (float*)d_out;

    // ---- workspace (within proven 410 MB footprint) ----
    char* ws = (char*)d_ws;
    const size_t SZH = (size_t)NN * 256 * 2;   // 102,400,000
    unsigned short* A  = (unsigned short*)ws;
    unsigned short* B  = (unsigned short*)(ws + SZH);   // M2 spans B..(B+2*SZH)
    char* Dr = ws + 3 * SZH;
    char* q = Dr;
    int* deg    = (int*)q; q += (size_t)NN * 4;
    int* rowptr = (int*)q; q += (size_t)(NN + 1) * 4;
    int* cursor = (int*)q; q += (size_t)NN * 4;
    int* srcs   = (int*)q; q += (size_t)NE * 4;
    int* eidx   = (int*)q; q += (size_t)NE * 4;
    int* bsum   = (int*)q; q += (size_t)NSCAN * 4;
    q = Dr + ((q - Dr + 63) & ~63ll);
    float*          eac = (float*)q; q += (size_t)NE * 16 * 4;          // 25.6 MB
    unsigned short* xh  = (unsigned short*)q; q += (size_t)NN * 128 * 2; // 51.2 MB
    int*   bat32 = (int*)q;   q += (size_t)NN * 4;                      // 0.8 MB
    float* sums  = (float*)q; q += (size_t)NG * 256 * 4;                // 4.2 MB
    char* p = ws + 4 * SZH;
    unsigned short* Wt1a = (unsigned short*)p; p += 128 * 256 * 2;
    unsigned short* Wt1b = (unsigned short*)p; p += 256 * 256 * 2;
    unsigned short* Wt2a = (unsigned short*)p; p += 256 * 256 * 2;
    unsigned short* Wt2b = (unsigned short*)p; p += 256 * 256 * 2;
    int* flag = (int*)p;

    detect_i64<<<1, 64, 0, stream>>>(ei, flag);
    bat_conv<<<(NN + 255) / 256, 256, 0, stream>>>(bat, flag, bat32);
    wt_conv<<<(128 * 256 + 255) / 256, 256, 0, stream>>>(W1a, Wt1a, 128, 256);
    wt_conv<<<(256 * 256 + 255) / 256, 256, 0, stream>>>(W1b, Wt1b, 256, 256);
    wt_conv<<<(256 * 256 + 255) / 256, 256, 0, stream>>>(W2a, Wt2a, 256, 256);
    wt_conv<<<(256 * 256 + 255) / 256, 256, 0, stream>>>(W2b, Wt2b, 256, 256);

    // ---- CSR build (once; shared by both layers) ----
    hipMemsetAsync(deg, 0, (size_t)NN * 4, stream);
    hipMemsetAsync(sums, 0, (size_t)NG * 256 * 4, stream);
    hist_dst<<<(NE + 255) / 256, 256, 0, stream>>>(ei, flag, deg);
    scan_bsum<<<NSCAN, 256, 0, stream>>>(deg, bsum);
    scan_carry<<<1, 64, 0, stream>>>(bsum, rowptr + NN);
    scan_final<<<NSCAN, 256, 0, stream>>>(deg, bsum, rowptr, cursor);
    fill_csr<<<(NE + 255) / 256, 256, 0, stream>>>(ei, flag, cursor, srcs, eidx);
    ea_perm<<<(NE + 255) / 256, 256, 0, stream>>>(ea, eidx, rowptr + NN, eac);
    x2bf<<<(NN * 128 / 4 + 255) / 256, 256, 0, stream>>>(x, xh);

    const int GM_BLK = NE / 32;   // 12500: 4 waves x 8 edge-slots per block
    const int GS_BLK = NN / 4;    // 50000: wave per node
    const int GG_BLK = NN / 64;   // 3125: GEMM m-blocks (64 rows, full N per block)

    // ---- layer 1 (D=128) ----
    msg_build<2, 8><<<GM_BLK, 256, 0, stream>>>(xh, eac, We1, be1, srcs, rowptr + NN, A);  // M1 -> A
    seg_sum<2><<<GS_BLK, 256, 0, stream>>>(A, rowptr, xh, B);                              // hin1 -> B
    gemm2_fused<128, 0><<<GG_BLK, 256, 0, stream>>>(B, Wt1a, b1a, Wt1b, b1b, A,
                                                    nullptr, nullptr);                     // h1 -> A

    // ---- layer 2 (D=256) ----
    msg_build<4, 8><<<GM_BLK, 256, 0, stream>>>(A, eac, We2, be2, srcs, rowptr + NN, B);   // M2 -> B
    seg_sum<4><<<GS_BLK, 256, 0, stream>>>(B, rowptr, A, A);                               // hin2 in-place A
    gemm2_fused<256, 1><<<GG_BLK, 256, 0, stream>>>(A, Wt2a, b2a, Wt2b, b2b, nullptr,
                                                    sums, bat32);                          // pool -> sums

    // ---- mean pool finish ----
    pool_div<<<NG, 256, 0, stream>>>(sums, bat32, out);
}